// Round 12
// baseline (485.934 us; speedup 1.0000x reference)
//
#include <hip/hip_runtime.h>

typedef __attribute__((ext_vector_type(8))) short short8;
typedef __attribute__((ext_vector_type(4))) float f32x4;
typedef __attribute__((ext_vector_type(2))) float f32x2;

constexpr int NN = 100000;
constexpr int EE = 1600000;
constexpr int DD = 128;
constexpr int CC = 47;
constexpr int NB = 391;      // buckets of 256 dst nodes (dst>>8)
constexpr int BSLOT = 5120;  // padded bucket capacity
constexpr int GB = 782;      // gemm grid (128 rows each)

// ---- workspace layout (bytes) ----
constexpr size_t OFF_XB   = 0;           // N*D bf16 running x (row-major)
constexpr size_t OFF_MB   = 25600000;    // N*D bf16 mean agg (row-major)
constexpr size_t OFF_HB   = 51200000;    // N*D bf16 pre-BN h (row-major)
constexpr size_t OFF_XQ   = 76800000;    // N*D fp8 gather shadow of x
constexpr size_t OFF_BIN  = 89600000;    // NB*BSLOT u32 binned packed edges
constexpr size_t OFF_CSR  = 97607680;    // E i32 (byte offsets: src*128)
constexpr size_t OFF_RP   = 104007680;   // N+1 i32 rowptr
constexpr size_t OFF_CUR  = 104407808;   // NB i32 bucket totals
constexpr size_t OFF_W    = 104411904;   // 104448 bf16 frag-ordered weights
constexpr size_t OFF_ST   = 104620800;   // 256 f32 stats (sum, sumsq)

static __device__ __forceinline__ float bf2f(unsigned short u) {
    return __uint_as_float(((unsigned)u) << 16);
}
static __device__ __forceinline__ unsigned short f2bf(float f) {
    unsigned u = __float_as_uint(f);
    unsigned r = (u + 0x7fffu + ((u >> 16) & 1u)) >> 16;
    return (unsigned short)r;
}
// pack 8 f32 -> 8 fp8 e4m3 (OCP on gfx950) as uint2
static __device__ __forceinline__ uint2 pack8_fp8(const float* f) {
    int w0 = 0, w1 = 0;
    w0 = __builtin_amdgcn_cvt_pk_fp8_f32(f[0], f[1], w0, false);
    w0 = __builtin_amdgcn_cvt_pk_fp8_f32(f[2], f[3], w0, true);
    w1 = __builtin_amdgcn_cvt_pk_fp8_f32(f[4], f[5], w1, false);
    w1 = __builtin_amdgcn_cvt_pk_fp8_f32(f[6], f[7], w1, true);
    return uint2{(unsigned)w0, (unsigned)w1};
}

// ---- merged prep: weights -> bf16 frag order (blocks 0..407),
//      x -> xb bf16 + xq fp8 (blocks 408..6657), zero cur (ids < NB) ----
__global__ void k_prep(const float* __restrict__ wl1, const float* __restrict__ wr1,
                       const float* __restrict__ wl2, const float* __restrict__ wr2,
                       const float* __restrict__ wl3, const float* __restrict__ wr3,
                       const float* __restrict__ lw, unsigned short* __restrict__ wdst,
                       const float* __restrict__ x, unsigned short* __restrict__ xb,
                       unsigned char* __restrict__ xq, int* __restrict__ cur) {
    int bid = blockIdx.x;
    int id = bid * 256 + threadIdx.x;
    if (id < NB) cur[id] = 0;
    if (bid < 408) {
        if (id < 98304) {
            int L = id >> 15;
            int r = id & 32767;
            int mat = r >> 14;
            int t = r & 16383;
            int j = t & 7, lane = (t >> 3) & 63, ct = (t >> 9) & 7, ks = t >> 12;
            int row = ct * 16 + (lane & 15);
            int col = ks * 32 + ((lane >> 4) << 3) + j;
            const float* src = (L == 0) ? (mat ? wr1 : wl1)
                             : (L == 1) ? (mat ? wr2 : wl2)
                                        : (mat ? wr3 : wl3);
            wdst[id] = f2bf(src[row * 128 + col]);
        } else if (id < 98304 + 6144) {
            int t = id - 98304;
            int j = t & 7, lane = (t >> 3) & 63, m = t >> 9;
            int ct = m % 3, ks = m / 3;
            int row = ct * 16 + (lane & 15);
            int col = ks * 32 + ((lane >> 4) << 3) + j;
            wdst[id] = (row < CC) ? f2bf(lw[row * 128 + col]) : (unsigned short)0;
        }
    } else {
        int i = ((bid - 408) * 256 + threadIdx.x) * 8;
        if (i >= NN * DD) return;
        float4 v1 = *(const float4*)(x + i);
        float4 v2 = *(const float4*)(x + i + 4);
        float f[8] = {v1.x, v1.y, v1.z, v1.w, v2.x, v2.y, v2.z, v2.w};
        short8 o;
        #pragma unroll
        for (int j = 0; j < 8; ++j) o[j] = (short)f2bf(f[j]);
        *(short8*)(xb + i) = o;
        *(uint2*)(xq + i) = pack8_fp8(f);
    }
}

// ---- pass A: bin edges by dst>>8 ----
__global__ __launch_bounds__(256) void k_bin(const int* __restrict__ ei,
                                             int* __restrict__ cur, int* __restrict__ bin) {
    __shared__ int cnt[NB];
    int t = threadIdx.x;
    for (int b = t; b < NB; b += 256) cnt[b] = 0;
    __syncthreads();
    int start = blockIdx.x * 3125;
    for (int i = t; i < 3125; i += 256) {
        int d = ei[EE + start + i];
        atomicAdd(&cnt[d >> 8], 1);
    }
    __syncthreads();
    int c[2], b0[2];
    #pragma unroll
    for (int k = 0; k < 2; ++k) {
        int b = t + k * 256;
        if (b < NB) { c[k] = cnt[b]; b0[k] = (c[k] > 0) ? atomicAdd(&cur[b], c[k]) : 0; }
    }
    __syncthreads();
    #pragma unroll
    for (int k = 0; k < 2; ++k) {
        int b = t + k * 256;
        if (b < NB) cnt[b] = b0[k];
    }
    __syncthreads();
    for (int i = t; i < 3125; i += 256) {
        int s = ei[start + i];
        int d = ei[EE + start + i];
        int b = d >> 8;
        int p = atomicAdd(&cnt[b], 1);
        if (p < BSLOT) bin[b * BSLOT + p] = (s << 8) | (d & 255);
    }
}

// ---- merged base+build: each block computes its own prefix of cur, then
//      builds its bucket's CSR segment (pre-scaled src byte offsets) ----
__global__ __launch_bounds__(256) void k_build(const int* __restrict__ cur,
                                               int* __restrict__ rp, const int* __restrict__ bin,
                                               int* __restrict__ csr) {
    __shared__ int lcnt[256], lsc[256], lrun[256], red[256];
    int b = blockIdx.x, t = threadIdx.x;
    // bb = sum cur[0..b-1] (each block computes its own base)
    int partial = 0;
    for (int i = t; i < b; i += 256) partial += cur[i];
    red[t] = partial;
    __syncthreads();
    for (int off = 128; off > 0; off >>= 1) {
        if (t < off) red[t] += red[t + off];
        __syncthreads();
    }
    int bb = red[0];
    __syncthreads();
    if (b == NB - 1 && t == 0) rp[NN] = bb + cur[b];

    int n0 = b << 8;
    int nodes = NN - n0; if (nodes > 256) nodes = 256;
    int tot = cur[b]; if (tot > BSLOT) tot = BSLOT;
    lcnt[t] = 0;
    __syncthreads();
    const int* bsrc = bin + b * BSLOT;
    for (int i = t; i < tot; i += 256) atomicAdd(&lcnt[bsrc[i] & 255], 1);
    __syncthreads();
    int c = lcnt[t];
    lsc[t] = c;
    __syncthreads();
    for (int off = 1; off < 256; off <<= 1) {
        int v = (t >= off) ? lsc[t - off] : 0;
        __syncthreads();
        lsc[t] += v;
        __syncthreads();
    }
    int excl = lsc[t] - c;
    if (t < nodes) rp[n0 + t] = bb + excl;
    lrun[t] = bb + excl;
    __syncthreads();
    for (int i = t; i < tot; i += 256) {
        int v = bsrc[i];
        int p = atomicAdd(&lrun[v & 255], 1);
        csr[p] = (v >> 8) << 7;   // pre-scaled byte offset into xq (src*128)
    }
}

// ---- mean aggregation from fp8 shadow: wave per node, 16 gathers per batch.
//      Block 0 also zeroes st for the following k_gemm (stream-ordered). ----
__global__ __launch_bounds__(256) void k_agg(const int* __restrict__ rp, const int* __restrict__ csr,
                                             const unsigned char* __restrict__ xq,
                                             unsigned short* __restrict__ mb,
                                             float* __restrict__ st) {
    if (blockIdx.x == 0) st[threadIdx.x] = 0.f;
    int node = blockIdx.x * 4 + (threadIdx.x >> 6);
    if (node >= NN) return;
    int lane = threadIdx.x & 63;
    int g = lane >> 4;            // edge sub-slot 0..3
    int cb = (lane & 15) << 3;    // 8-element column window (byte == elem for fp8)
    int s0 = rp[node], s1 = rp[node + 1];
    int deg = s1 - s0;
    f32x2 acc0 = {0.f, 0.f}, acc1 = {0.f, 0.f}, acc2 = {0.f, 0.f}, acc3 = {0.f, 0.f};
    int nb = deg >> 4;            // uniform full batches of 16 edges
    int e = s0 + g;
    for (int k = 0; k < nb; ++k) {
        int i0 = csr[e];
        int i1 = csr[e + 4];
        int i2 = csr[e + 8];
        int i3 = csr[e + 12];
        uint2 v0 = *(const uint2*)(xq + i0 + cb);
        uint2 v1 = *(const uint2*)(xq + i1 + cb);
        uint2 v2 = *(const uint2*)(xq + i2 + cb);
        uint2 v3 = *(const uint2*)(xq + i3 + cb);
        acc0 += __builtin_amdgcn_cvt_pk_f32_fp8(v0.x, false);
        acc1 += __builtin_amdgcn_cvt_pk_f32_fp8(v0.x, true);
        acc2 += __builtin_amdgcn_cvt_pk_f32_fp8(v0.y, false);
        acc3 += __builtin_amdgcn_cvt_pk_f32_fp8(v0.y, true);
        acc0 += __builtin_amdgcn_cvt_pk_f32_fp8(v1.x, false);
        acc1 += __builtin_amdgcn_cvt_pk_f32_fp8(v1.x, true);
        acc2 += __builtin_amdgcn_cvt_pk_f32_fp8(v1.y, false);
        acc3 += __builtin_amdgcn_cvt_pk_f32_fp8(v1.y, true);
        acc0 += __builtin_amdgcn_cvt_pk_f32_fp8(v2.x, false);
        acc1 += __builtin_amdgcn_cvt_pk_f32_fp8(v2.x, true);
        acc2 += __builtin_amdgcn_cvt_pk_f32_fp8(v2.y, false);
        acc3 += __builtin_amdgcn_cvt_pk_f32_fp8(v2.y, true);
        acc0 += __builtin_amdgcn_cvt_pk_f32_fp8(v3.x, false);
        acc1 += __builtin_amdgcn_cvt_pk_f32_fp8(v3.x, true);
        acc2 += __builtin_amdgcn_cvt_pk_f32_fp8(v3.y, false);
        acc3 += __builtin_amdgcn_cvt_pk_f32_fp8(v3.y, true);
        e += 16;
    }
    for (; e < s1; e += 4) {      // tail: < 16 edges, slot-divergent
        int i0 = csr[e];
        uint2 v0 = *(const uint2*)(xq + i0 + cb);
        acc0 += __builtin_amdgcn_cvt_pk_f32_fp8(v0.x, false);
        acc1 += __builtin_amdgcn_cvt_pk_f32_fp8(v0.x, true);
        acc2 += __builtin_amdgcn_cvt_pk_f32_fp8(v0.y, false);
        acc3 += __builtin_amdgcn_cvt_pk_f32_fp8(v0.y, true);
    }
    float acc[8] = {acc0[0], acc0[1], acc1[0], acc1[1],
                    acc2[0], acc2[1], acc3[0], acc3[1]};
    #pragma unroll
    for (int j = 0; j < 8; ++j) {
        acc[j] += __shfl_xor(acc[j], 16);
        acc[j] += __shfl_xor(acc[j], 32);
    }
    if (g == 0) {
        float inv = 1.0f / (float)(deg > 1 ? deg : 1);
        short8 o;
        #pragma unroll
        for (int j = 0; j < 8; ++j) o[j] = (short)f2bf(acc[j] * inv);
        *(short8*)(mb + (size_t)node * 128 + cb) = o;
    }
}

// ---- fused SAGE GEMM v3b: identical to v3 but __launch_bounds__(512,8):
// VGPR=32 and LDS=40.96KB both permit 4 blocks/CU (32 waves) — the (512,6)
// bound was artificially capping occupancy at 3 blocks/24 waves. ----
__global__ __launch_bounds__(512, 8) void k_gemm(const unsigned short* __restrict__ xb,
                                                 const unsigned short* __restrict__ mb,
                                                 const unsigned short* __restrict__ wf,
                                                 const float* __restrict__ bias,
                                                 unsigned short* __restrict__ hb,
                                                 float* __restrict__ st) {
    __shared__ unsigned short wsh[16384];   // 32 KB: one matrix at a time
    __shared__ float rbuf[2048];            // 8 waves x 256 stat partials
    int tid = threadIdx.x;
    int wave = tid >> 6, lane = tid & 63, q = lane >> 4, l15 = lane & 15;
    int rowbase = blockIdx.x * 128 + wave * 16;
    int arow = rowbase + l15;

    f32x4 acc[8];
    #pragma unroll
    for (int ct = 0; ct < 8; ++ct) {
        float bv = bias[ct * 16 + l15];
        f32x4 t = {bv, bv, bv, bv};
        acc[ct] = t;
    }

    #pragma unroll
    for (int mat = 0; mat < 2; ++mat) {
        const unsigned short* src = mat ? mb : xb;
        const int4* wsrc = (const int4*)(wf + (mat << 14));
        if (mat) __syncthreads();           // drain mat-0 LDS reads before overwrite
        #pragma unroll
        for (int i = 0; i < 4; ++i)
            ((int4*)wsh)[tid + i * 512] = wsrc[tid + i * 512];
        __syncthreads();
        #pragma unroll
        for (int ks = 0; ks < 4; ++ks) {
            short8 a;
            if (arow < NN) a = *(const short8*)(src + (size_t)arow * 128 + ks * 32 + (q << 3));
            else           a = short8{0,0,0,0,0,0,0,0};
            #pragma unroll
            for (int ct = 0; ct < 8; ++ct) {
                short8 b = *(const short8*)(wsh + ((ks * 8 + ct) << 9) + (lane << 3));
                acc[ct] = __builtin_amdgcn_mfma_f32_16x16x32_bf16(a, b, acc[ct], 0, 0, 0);
            }
        }
    }

    // epilogue: bf16 store + per-block column stat partials -> device atomics
    #pragma unroll
    for (int ct = 0; ct < 8; ++ct) {
        int colg = ct * 16 + l15;
        float sv = 0.f, qv = 0.f;
        #pragma unroll
        for (int r = 0; r < 4; ++r) {
            int row = rowbase + (q << 2) + r;
            if (row < NN) {
                float v = acc[ct][r];
                hb[(size_t)row * 128 + colg] = f2bf(v);
                sv += v; qv += v * v;
            }
        }
        sv += __shfl_xor(sv, 16); sv += __shfl_xor(sv, 32);
        qv += __shfl_xor(qv, 16); qv += __shfl_xor(qv, 32);
        if (q == 0) {
            rbuf[wave * 256 + colg] = sv;
            rbuf[wave * 256 + 128 + colg] = qv;
        }
    }
    __syncthreads();
    if (tid < 256) {
        float v = 0.f;
        #pragma unroll
        for (int w = 0; w < 8; ++w) v += rbuf[w * 256 + tid];
        atomicAdd(&st[tid], v);
    }
}

// ---- BatchNorm + ReLU + residual; emits bf16 x and fp8 shadow (layers 1,2) ----
__global__ void k_bn(const unsigned short* __restrict__ hb,
                     const float* __restrict__ stats, const float* __restrict__ gam,
                     const float* __restrict__ bet, unsigned short* __restrict__ xb,
                     unsigned char* __restrict__ xq) {
    int i = (blockIdx.x * 256 + threadIdx.x) * 8;
    if (i >= NN * DD) return;
    int col = i & 127;
    const float invN = 1.0f / (float)NN;
    short8 hv = *(const short8*)(hb + i);
    short8 xv = *(const short8*)(xb + i);
    short8 o;
    float f[8];
    #pragma unroll
    for (int j = 0; j < 8; ++j) {
        int c = col + j;
        float mu = stats[c] * invN;
        float var = stats[128 + c] * invN - mu * mu;
        float sc = rsqrtf(var + 1e-5f) * gam[c];
        float val = (bf2f((unsigned short)hv[j]) - mu) * sc + bet[c];
        float r = bf2f((unsigned short)xv[j]) + (val > 0.f ? val : 0.f);
        f[j] = r;
        o[j] = (short)f2bf(r);
    }
    *(short8*)(xb + i) = o;
    *(uint2*)(xq + i) = pack8_fp8(f);
}

// ---- fused layer-3 BN + classifier: BN+ReLU+residual into LDS tile, then
//      out = xnew @ lin_W^T + lin_b. No xb/xq writes, no separate k_final. ----
__global__ __launch_bounds__(256) void k_bnfinal(const unsigned short* __restrict__ hb,
                                                 const unsigned short* __restrict__ xb,
                                                 const float* __restrict__ stats,
                                                 const float* __restrict__ gam,
                                                 const float* __restrict__ bet,
                                                 const unsigned short* __restrict__ wf,
                                                 const float* __restrict__ bias,
                                                 float* __restrict__ out) {
    __shared__ unsigned short xt[128 * 132];  // 33 KB padded tile (132: 2-way banks)
    __shared__ unsigned short wsh[6144];      // 12 KB linW frags
    int tid = threadIdx.x;
    #pragma unroll
    for (int i = 0; i < 3; ++i) {
        int idx = tid + i * 256;
        if (idx < 768) ((int4*)wsh)[idx] = ((const int4*)wf)[idx];
    }

    int rowb0 = blockIdx.x * 128;
    const float invN = 1.0f / (float)NN;
    #pragma unroll
    for (int it = 0; it < 8; ++it) {
        int ch = tid + it * 256;       // 2048: 128 rows x 16 col-chunks
        int lrow = ch >> 4, seg = ch & 15;
        int grow = rowb0 + lrow;
        short8 o = short8{0,0,0,0,0,0,0,0};
        if (grow < NN) {
            short8 hv = *(const short8*)(hb + (size_t)grow * 128 + seg * 8);
            short8 xv = *(const short8*)(xb + (size_t)grow * 128 + seg * 8);
            #pragma unroll
            for (int j = 0; j < 8; ++j) {
                int c = seg * 8 + j;
                float mu = stats[c] * invN;
                float var = stats[128 + c] * invN - mu * mu;
                float sc = rsqrtf(var + 1e-5f) * gam[c];
                float val = (bf2f((unsigned short)hv[j]) - mu) * sc + bet[c];
                float r = bf2f((unsigned short)xv[j]) + (val > 0.f ? val : 0.f);
                o[j] = (short)f2bf(r);
            }
        }
        *(short8*)(xt + lrow * 132 + seg * 8) = o;
    }
    __syncthreads();

    int wave = tid >> 6, lane = tid & 63, q = lane >> 4, l15 = lane & 15;
    int lrow0 = wave * 32;

    f32x4 acc[2][3];
    #pragma unroll
    for (int ct = 0; ct < 3; ++ct) {
        int colg = ct * 16 + l15;
        float bv = (colg < CC) ? bias[colg] : 0.f;
        f32x4 t = {bv, bv, bv, bv};
        acc[0][ct] = t; acc[1][ct] = t;
    }
    #pragma unroll
    for (int ks = 0; ks < 4; ++ks) {
        short8 a[2];
        #pragma unroll
        for (int rt = 0; rt < 2; ++rt)
            a[rt] = *(const short8*)(xt + (lrow0 + rt * 16 + l15) * 132 + ks * 32 + (q << 3));
        #pragma unroll
        for (int ct = 0; ct < 3; ++ct) {
            short8 b = *(const short8*)(wsh + ((ks * 3 + ct) << 9) + (lane << 3));
            #pragma unroll
            for (int rt = 0; rt < 2; ++rt)
                acc[rt][ct] = __builtin_amdgcn_mfma_f32_16x16x32_bf16(a[rt], b, acc[rt][ct], 0, 0, 0);
        }
    }
    #pragma unroll
    for (int ct = 0; ct < 3; ++ct) {
        int colg = ct * 16 + l15;
        if (colg >= CC) continue;
        #pragma unroll
        for (int rt = 0; rt < 2; ++rt) {
            #pragma unroll
            for (int r = 0; r < 4; ++r) {
                int row = rowb0 + lrow0 + rt * 16 + (q << 2) + r;
                if (row < NN) out[(size_t)row * CC + colg] = acc[rt][ct][r];
            }
        }
    }
}

extern "C" void kernel_launch(void* const* d_in, const int* in_sizes, int n_in,
                              void* d_out, int out_size, void* d_ws, size_t ws_size,
                              hipStream_t stream) {
    const float* x   = (const float*)d_in[0];
    const int*   ei  = (const int*)d_in[1];
    const float* Wl[3]  = {(const float*)d_in[2],  (const float*)d_in[7],  (const float*)d_in[12]};
    const float* bl[3]  = {(const float*)d_in[3],  (const float*)d_in[8],  (const float*)d_in[13]};
    const float* Wr[3]  = {(const float*)d_in[4],  (const float*)d_in[9],  (const float*)d_in[14]};
    const float* bng[3] = {(const float*)d_in[5],  (const float*)d_in[10], (const float*)d_in[15]};
    const float* bnb[3] = {(const float*)d_in[6],  (const float*)d_in[11], (const float*)d_in[16]};
    const float* linW = (const float*)d_in[17];
    const float* linb = (const float*)d_in[18];

    char* ws = (char*)d_ws;
    unsigned short* xb   = (unsigned short*)(ws + OFF_XB);
    unsigned short* mb   = (unsigned short*)(ws + OFF_MB);
    unsigned short* hb   = (unsigned short*)(ws + OFF_HB);
    unsigned char*  xq   = (unsigned char*)(ws + OFF_XQ);
    int*            bin  = (int*)(ws + OFF_BIN);
    int*            csr  = (int*)(ws + OFF_CSR);
    int*            rp   = (int*)(ws + OFF_RP);
    int*            cur  = (int*)(ws + OFF_CUR);
    unsigned short* wfr  = (unsigned short*)(ws + OFF_W);
    float*          st   = (float*)(ws + OFF_ST);

    k_prep<<<6658, 256, 0, stream>>>(Wl[0], Wr[0], Wl[1], Wr[1], Wl[2], Wr[2], linW, wfr,
                                     x, xb, xq, cur);
    k_bin<<<512, 256, 0, stream>>>(ei, cur, bin);
    k_build<<<NB, 256, 0, stream>>>(cur, rp, bin, csr);

    for (int l = 0; l < 3; ++l) {
        const unsigned short* wfp = wfr + (size_t)l * 32768;
        k_agg<<<25000, 256, 0, stream>>>(rp, csr, xq, mb, st);
        k_gemm<<<GB, 512, 0, stream>>>(xb, mb, wfp, bl[l], hb, st);
        if (l < 2)
            k_bn<<<6250, 256, 0, stream>>>(hb, st, bng[l], bnb[l], xb, xq);
    }
    k_bnfinal<<<GB, 256, 0, stream>>>(hb, xb, st, bng[2], bnb[2], wfr + 98304, linb,
                                      (float*)d_out);
}

// Round 13
// 478.669 us; speedup vs baseline: 1.0152x; 1.0152x over previous
//
#include <hip/hip_runtime.h>

typedef __attribute__((ext_vector_type(8))) short short8;
typedef __attribute__((ext_vector_type(4))) float f32x4;
typedef __attribute__((ext_vector_type(2))) float f32x2;

constexpr int NN = 100000;
constexpr int EE = 1600000;
constexpr int DD = 128;
constexpr int CC = 47;
constexpr int NB = 391;      // buckets of 256 dst nodes (dst>>8)
constexpr int BSLOT = 5120;  // padded bucket capacity
constexpr int GB = 782;      // gemm grid (128 rows each)

// ---- workspace layout (bytes) ----
constexpr size_t OFF_XB   = 0;           // N*D bf16 running x (row-major)
constexpr size_t OFF_MB   = 25600000;    // N*D bf16 mean agg (row-major)
constexpr size_t OFF_HB   = 51200000;    // N*D bf16 pre-BN h (row-major)
constexpr size_t OFF_XQ   = 76800000;    // N*D fp8 gather shadow of x
constexpr size_t OFF_BIN  = 89600000;    // NB*BSLOT u32 binned packed edges
constexpr size_t OFF_CSR  = 97607680;    // E i32 (byte offsets: src*128)
constexpr size_t OFF_RP   = 104007680;   // N+1 i32 rowptr
constexpr size_t OFF_CUR  = 104407808;   // NB i32 bucket totals
constexpr size_t OFF_W    = 104411904;   // 104448 bf16 frag-ordered weights
constexpr size_t OFF_ST   = 104620800;   // 256 f32 stats (sum, sumsq)

static __device__ __forceinline__ float bf2f(unsigned short u) {
    return __uint_as_float(((unsigned)u) << 16);
}
static __device__ __forceinline__ unsigned short f2bf(float f) {
    unsigned u = __float_as_uint(f);
    unsigned r = (u + 0x7fffu + ((u >> 16) & 1u)) >> 16;
    return (unsigned short)r;
}
// pack 8 f32 -> 8 fp8 e4m3 (OCP on gfx950) as uint2
static __device__ __forceinline__ uint2 pack8_fp8(const float* f) {
    int w0 = 0, w1 = 0;
    w0 = __builtin_amdgcn_cvt_pk_fp8_f32(f[0], f[1], w0, false);
    w0 = __builtin_amdgcn_cvt_pk_fp8_f32(f[2], f[3], w0, true);
    w1 = __builtin_amdgcn_cvt_pk_fp8_f32(f[4], f[5], w1, false);
    w1 = __builtin_amdgcn_cvt_pk_fp8_f32(f[6], f[7], w1, true);
    return uint2{(unsigned)w0, (unsigned)w1};
}

// ---- merged prep: weights -> bf16 frag order (blocks 0..407),
//      x -> xb bf16 + xq fp8 (blocks 408..6657), zero cur (ids < NB) ----
__global__ void k_prep(const float* __restrict__ wl1, const float* __restrict__ wr1,
                       const float* __restrict__ wl2, const float* __restrict__ wr2,
                       const float* __restrict__ wl3, const float* __restrict__ wr3,
                       const float* __restrict__ lw, unsigned short* __restrict__ wdst,
                       const float* __restrict__ x, unsigned short* __restrict__ xb,
                       unsigned char* __restrict__ xq, int* __restrict__ cur) {
    int bid = blockIdx.x;
    int id = bid * 256 + threadIdx.x;
    if (id < NB) cur[id] = 0;
    if (bid < 408) {
        if (id < 98304) {
            int L = id >> 15;
            int r = id & 32767;
            int mat = r >> 14;
            int t = r & 16383;
            int j = t & 7, lane = (t >> 3) & 63, ct = (t >> 9) & 7, ks = t >> 12;
            int row = ct * 16 + (lane & 15);
            int col = ks * 32 + ((lane >> 4) << 3) + j;
            const float* src = (L == 0) ? (mat ? wr1 : wl1)
                             : (L == 1) ? (mat ? wr2 : wl2)
                                        : (mat ? wr3 : wl3);
            wdst[id] = f2bf(src[row * 128 + col]);
        } else if (id < 98304 + 6144) {
            int t = id - 98304;
            int j = t & 7, lane = (t >> 3) & 63, m = t >> 9;
            int ct = m % 3, ks = m / 3;
            int row = ct * 16 + (lane & 15);
            int col = ks * 32 + ((lane >> 4) << 3) + j;
            wdst[id] = (row < CC) ? f2bf(lw[row * 128 + col]) : (unsigned short)0;
        }
    } else {
        int i = ((bid - 408) * 256 + threadIdx.x) * 8;
        if (i >= NN * DD) return;
        float4 v1 = *(const float4*)(x + i);
        float4 v2 = *(const float4*)(x + i + 4);
        float f[8] = {v1.x, v1.y, v1.z, v1.w, v2.x, v2.y, v2.z, v2.w};
        short8 o;
        #pragma unroll
        for (int j = 0; j < 8; ++j) o[j] = (short)f2bf(f[j]);
        *(short8*)(xb + i) = o;
        *(uint2*)(xq + i) = pack8_fp8(f);
    }
}

// ---- pass A: bin edges by dst>>8 ----
__global__ __launch_bounds__(256) void k_bin(const int* __restrict__ ei,
                                             int* __restrict__ cur, int* __restrict__ bin) {
    __shared__ int cnt[NB];
    int t = threadIdx.x;
    for (int b = t; b < NB; b += 256) cnt[b] = 0;
    __syncthreads();
    int start = blockIdx.x * 3125;
    for (int i = t; i < 3125; i += 256) {
        int d = ei[EE + start + i];
        atomicAdd(&cnt[d >> 8], 1);
    }
    __syncthreads();
    int c[2], b0[2];
    #pragma unroll
    for (int k = 0; k < 2; ++k) {
        int b = t + k * 256;
        if (b < NB) { c[k] = cnt[b]; b0[k] = (c[k] > 0) ? atomicAdd(&cur[b], c[k]) : 0; }
    }
    __syncthreads();
    #pragma unroll
    for (int k = 0; k < 2; ++k) {
        int b = t + k * 256;
        if (b < NB) cnt[b] = b0[k];
    }
    __syncthreads();
    for (int i = t; i < 3125; i += 256) {
        int s = ei[start + i];
        int d = ei[EE + start + i];
        int b = d >> 8;
        int p = atomicAdd(&cnt[b], 1);
        if (p < BSLOT) bin[b * BSLOT + p] = (s << 8) | (d & 255);
    }
}

// ---- merged base+build: each block computes its own prefix of cur, then
//      builds its bucket's CSR segment (pre-scaled src byte offsets) ----
__global__ __launch_bounds__(256) void k_build(const int* __restrict__ cur,
                                               int* __restrict__ rp, const int* __restrict__ bin,
                                               int* __restrict__ csr) {
    __shared__ int lcnt[256], lsc[256], lrun[256], red[256];
    int b = blockIdx.x, t = threadIdx.x;
    // bb = sum cur[0..b-1] (each block computes its own base)
    int partial = 0;
    for (int i = t; i < b; i += 256) partial += cur[i];
    red[t] = partial;
    __syncthreads();
    for (int off = 128; off > 0; off >>= 1) {
        if (t < off) red[t] += red[t + off];
        __syncthreads();
    }
    int bb = red[0];
    __syncthreads();
    if (b == NB - 1 && t == 0) rp[NN] = bb + cur[b];

    int n0 = b << 8;
    int nodes = NN - n0; if (nodes > 256) nodes = 256;
    int tot = cur[b]; if (tot > BSLOT) tot = BSLOT;
    lcnt[t] = 0;
    __syncthreads();
    const int* bsrc = bin + b * BSLOT;
    for (int i = t; i < tot; i += 256) atomicAdd(&lcnt[bsrc[i] & 255], 1);
    __syncthreads();
    int c = lcnt[t];
    lsc[t] = c;
    __syncthreads();
    for (int off = 1; off < 256; off <<= 1) {
        int v = (t >= off) ? lsc[t - off] : 0;
        __syncthreads();
        lsc[t] += v;
        __syncthreads();
    }
    int excl = lsc[t] - c;
    if (t < nodes) rp[n0 + t] = bb + excl;
    lrun[t] = bb + excl;
    __syncthreads();
    for (int i = t; i < tot; i += 256) {
        int v = bsrc[i];
        int p = atomicAdd(&lrun[v & 255], 1);
        csr[p] = (v >> 8) << 7;   // pre-scaled byte offset into xq (src*128)
    }
}

// ---- mean aggregation from fp8 shadow: wave per node, 16 gathers per batch.
//      Block 0 also zeroes st for the following k_gemm (stream-ordered). ----
__global__ __launch_bounds__(256) void k_agg(const int* __restrict__ rp, const int* __restrict__ csr,
                                             const unsigned char* __restrict__ xq,
                                             unsigned short* __restrict__ mb,
                                             float* __restrict__ st) {
    if (blockIdx.x == 0) st[threadIdx.x] = 0.f;
    int node = blockIdx.x * 4 + (threadIdx.x >> 6);
    if (node >= NN) return;
    int lane = threadIdx.x & 63;
    int g = lane >> 4;            // edge sub-slot 0..3
    int cb = (lane & 15) << 3;    // 8-element column window (byte == elem for fp8)
    int s0 = rp[node], s1 = rp[node + 1];
    int deg = s1 - s0;
    f32x2 acc0 = {0.f, 0.f}, acc1 = {0.f, 0.f}, acc2 = {0.f, 0.f}, acc3 = {0.f, 0.f};
    int nb = deg >> 4;            // uniform full batches of 16 edges
    int e = s0 + g;
    for (int k = 0; k < nb; ++k) {
        int i0 = csr[e];
        int i1 = csr[e + 4];
        int i2 = csr[e + 8];
        int i3 = csr[e + 12];
        uint2 v0 = *(const uint2*)(xq + i0 + cb);
        uint2 v1 = *(const uint2*)(xq + i1 + cb);
        uint2 v2 = *(const uint2*)(xq + i2 + cb);
        uint2 v3 = *(const uint2*)(xq + i3 + cb);
        acc0 += __builtin_amdgcn_cvt_pk_f32_fp8(v0.x, false);
        acc1 += __builtin_amdgcn_cvt_pk_f32_fp8(v0.x, true);
        acc2 += __builtin_amdgcn_cvt_pk_f32_fp8(v0.y, false);
        acc3 += __builtin_amdgcn_cvt_pk_f32_fp8(v0.y, true);
        acc0 += __builtin_amdgcn_cvt_pk_f32_fp8(v1.x, false);
        acc1 += __builtin_amdgcn_cvt_pk_f32_fp8(v1.x, true);
        acc2 += __builtin_amdgcn_cvt_pk_f32_fp8(v1.y, false);
        acc3 += __builtin_amdgcn_cvt_pk_f32_fp8(v1.y, true);
        acc0 += __builtin_amdgcn_cvt_pk_f32_fp8(v2.x, false);
        acc1 += __builtin_amdgcn_cvt_pk_f32_fp8(v2.x, true);
        acc2 += __builtin_amdgcn_cvt_pk_f32_fp8(v2.y, false);
        acc3 += __builtin_amdgcn_cvt_pk_f32_fp8(v2.y, true);
        acc0 += __builtin_amdgcn_cvt_pk_f32_fp8(v3.x, false);
        acc1 += __builtin_amdgcn_cvt_pk_f32_fp8(v3.x, true);
        acc2 += __builtin_amdgcn_cvt_pk_f32_fp8(v3.y, false);
        acc3 += __builtin_amdgcn_cvt_pk_f32_fp8(v3.y, true);
        e += 16;
    }
    for (; e < s1; e += 4) {      // tail: < 16 edges, slot-divergent
        int i0 = csr[e];
        uint2 v0 = *(const uint2*)(xq + i0 + cb);
        acc0 += __builtin_amdgcn_cvt_pk_f32_fp8(v0.x, false);
        acc1 += __builtin_amdgcn_cvt_pk_f32_fp8(v0.x, true);
        acc2 += __builtin_amdgcn_cvt_pk_f32_fp8(v0.y, false);
        acc3 += __builtin_amdgcn_cvt_pk_f32_fp8(v0.y, true);
    }
    float acc[8] = {acc0[0], acc0[1], acc1[0], acc1[1],
                    acc2[0], acc2[1], acc3[0], acc3[1]};
    #pragma unroll
    for (int j = 0; j < 8; ++j) {
        acc[j] += __shfl_xor(acc[j], 16);
        acc[j] += __shfl_xor(acc[j], 32);
    }
    if (g == 0) {
        float inv = 1.0f / (float)(deg > 1 ? deg : 1);
        short8 o;
        #pragma unroll
        for (int j = 0; j < 8; ++j) o[j] = (short)f2bf(acc[j] * inv);
        *(short8*)(mb + (size_t)node * 128 + cb) = o;
    }
}

// ---- fused SAGE GEMM v3 (locked): h = x@Wl^T + bl + mean@Wr^T.
// 512 thr / 8 waves / LDS-staged B / launch_bounds(512,6) = 3 blocks/CU,
// 24 waves. Measured best; (512,8) 4-block config regressed (exact-fit LDS),
// register pipelining spills, global-B doubles L2 traffic. ----
__global__ __launch_bounds__(512, 6) void k_gemm(const unsigned short* __restrict__ xb,
                                                 const unsigned short* __restrict__ mb,
                                                 const unsigned short* __restrict__ wf,
                                                 const float* __restrict__ bias,
                                                 unsigned short* __restrict__ hb,
                                                 float* __restrict__ st) {
    __shared__ unsigned short wsh[16384];   // 32 KB: one matrix at a time
    __shared__ float rbuf[2048];            // 8 waves x 256 stat partials
    int tid = threadIdx.x;
    int wave = tid >> 6, lane = tid & 63, q = lane >> 4, l15 = lane & 15;
    int rowbase = blockIdx.x * 128 + wave * 16;
    int arow = rowbase + l15;

    f32x4 acc[8];
    #pragma unroll
    for (int ct = 0; ct < 8; ++ct) {
        float bv = bias[ct * 16 + l15];
        f32x4 t = {bv, bv, bv, bv};
        acc[ct] = t;
    }

    #pragma unroll
    for (int mat = 0; mat < 2; ++mat) {
        const unsigned short* src = mat ? mb : xb;
        const int4* wsrc = (const int4*)(wf + (mat << 14));
        if (mat) __syncthreads();           // drain mat-0 LDS reads before overwrite
        #pragma unroll
        for (int i = 0; i < 4; ++i)
            ((int4*)wsh)[tid + i * 512] = wsrc[tid + i * 512];
        __syncthreads();
        #pragma unroll
        for (int ks = 0; ks < 4; ++ks) {
            short8 a;
            if (arow < NN) a = *(const short8*)(src + (size_t)arow * 128 + ks * 32 + (q << 3));
            else           a = short8{0,0,0,0,0,0,0,0};
            #pragma unroll
            for (int ct = 0; ct < 8; ++ct) {
                short8 b = *(const short8*)(wsh + ((ks * 8 + ct) << 9) + (lane << 3));
                acc[ct] = __builtin_amdgcn_mfma_f32_16x16x32_bf16(a, b, acc[ct], 0, 0, 0);
            }
        }
    }

    // epilogue: bf16 store + per-block column stat partials -> device atomics
    #pragma unroll
    for (int ct = 0; ct < 8; ++ct) {
        int colg = ct * 16 + l15;
        float sv = 0.f, qv = 0.f;
        #pragma unroll
        for (int r = 0; r < 4; ++r) {
            int row = rowbase + (q << 2) + r;
            if (row < NN) {
                float v = acc[ct][r];
                hb[(size_t)row * 128 + colg] = f2bf(v);
                sv += v; qv += v * v;
            }
        }
        sv += __shfl_xor(sv, 16); sv += __shfl_xor(sv, 32);
        qv += __shfl_xor(qv, 16); qv += __shfl_xor(qv, 32);
        if (q == 0) {
            rbuf[wave * 256 + colg] = sv;
            rbuf[wave * 256 + 128 + colg] = qv;
        }
    }
    __syncthreads();
    if (tid < 256) {
        float v = 0.f;
        #pragma unroll
        for (int w = 0; w < 8; ++w) v += rbuf[w * 256 + tid];
        atomicAdd(&st[tid], v);
    }
}

// ---- BatchNorm + ReLU + residual; emits bf16 x and fp8 shadow (layers 1,2) ----
__global__ void k_bn(const unsigned short* __restrict__ hb,
                     const float* __restrict__ stats, const float* __restrict__ gam,
                     const float* __restrict__ bet, unsigned short* __restrict__ xb,
                     unsigned char* __restrict__ xq) {
    int i = (blockIdx.x * 256 + threadIdx.x) * 8;
    if (i >= NN * DD) return;
    int col = i & 127;
    const float invN = 1.0f / (float)NN;
    short8 hv = *(const short8*)(hb + i);
    short8 xv = *(const short8*)(xb + i);
    short8 o;
    float f[8];
    #pragma unroll
    for (int j = 0; j < 8; ++j) {
        int c = col + j;
        float mu = stats[c] * invN;
        float var = stats[128 + c] * invN - mu * mu;
        float sc = rsqrtf(var + 1e-5f) * gam[c];
        float val = (bf2f((unsigned short)hv[j]) - mu) * sc + bet[c];
        float r = bf2f((unsigned short)xv[j]) + (val > 0.f ? val : 0.f);
        f[j] = r;
        o[j] = (short)f2bf(r);
    }
    *(short8*)(xb + i) = o;
    *(uint2*)(xq + i) = pack8_fp8(f);
}

// ---- fused layer-3 BN + classifier: BN+ReLU+residual into LDS tile, then
//      out = xnew @ lin_W^T + lin_b. No xb/xq writes, no separate k_final. ----
__global__ __launch_bounds__(256) void k_bnfinal(const unsigned short* __restrict__ hb,
                                                 const unsigned short* __restrict__ xb,
                                                 const float* __restrict__ stats,
                                                 const float* __restrict__ gam,
                                                 const float* __restrict__ bet,
                                                 const unsigned short* __restrict__ wf,
                                                 const float* __restrict__ bias,
                                                 float* __restrict__ out) {
    __shared__ unsigned short xt[128 * 132];  // 33 KB padded tile (132: 2-way banks)
    __shared__ unsigned short wsh[6144];      // 12 KB linW frags
    int tid = threadIdx.x;
    #pragma unroll
    for (int i = 0; i < 3; ++i) {
        int idx = tid + i * 256;
        if (idx < 768) ((int4*)wsh)[idx] = ((const int4*)wf)[idx];
    }

    int rowb0 = blockIdx.x * 128;
    const float invN = 1.0f / (float)NN;
    #pragma unroll
    for (int it = 0; it < 8; ++it) {
        int ch = tid + it * 256;       // 2048: 128 rows x 16 col-chunks
        int lrow = ch >> 4, seg = ch & 15;
        int grow = rowb0 + lrow;
        short8 o = short8{0,0,0,0,0,0,0,0};
        if (grow < NN) {
            short8 hv = *(const short8*)(hb + (size_t)grow * 128 + seg * 8);
            short8 xv = *(const short8*)(xb + (size_t)grow * 128 + seg * 8);
            #pragma unroll
            for (int j = 0; j < 8; ++j) {
                int c = seg * 8 + j;
                float mu = stats[c] * invN;
                float var = stats[128 + c] * invN - mu * mu;
                float sc = rsqrtf(var + 1e-5f) * gam[c];
                float val = (bf2f((unsigned short)hv[j]) - mu) * sc + bet[c];
                float r = bf2f((unsigned short)xv[j]) + (val > 0.f ? val : 0.f);
                o[j] = (short)f2bf(r);
            }
        }
        *(short8*)(xt + lrow * 132 + seg * 8) = o;
    }
    __syncthreads();

    int wave = tid >> 6, lane = tid & 63, q = lane >> 4, l15 = lane & 15;
    int lrow0 = wave * 32;

    f32x4 acc[2][3];
    #pragma unroll
    for (int ct = 0; ct < 3; ++ct) {
        int colg = ct * 16 + l15;
        float bv = (colg < CC) ? bias[colg] : 0.f;
        f32x4 t = {bv, bv, bv, bv};
        acc[0][ct] = t; acc[1][ct] = t;
    }
    #pragma unroll
    for (int ks = 0; ks < 4; ++ks) {
        short8 a[2];
        #pragma unroll
        for (int rt = 0; rt < 2; ++rt)
            a[rt] = *(const short8*)(xt + (lrow0 + rt * 16 + l15) * 132 + ks * 32 + (q << 3));
        #pragma unroll
        for (int ct = 0; ct < 3; ++ct) {
            short8 b = *(const short8*)(wsh + ((ks * 3 + ct) << 9) + (lane << 3));
            #pragma unroll
            for (int rt = 0; rt < 2; ++rt)
                acc[rt][ct] = __builtin_amdgcn_mfma_f32_16x16x32_bf16(a[rt], b, acc[rt][ct], 0, 0, 0);
        }
    }
    #pragma unroll
    for (int ct = 0; ct < 3; ++ct) {
        int colg = ct * 16 + l15;
        if (colg >= CC) continue;
        #pragma unroll
        for (int rt = 0; rt < 2; ++rt) {
            #pragma unroll
            for (int r = 0; r < 4; ++r) {
                int row = rowb0 + lrow0 + rt * 16 + (q << 2) + r;
                if (row < NN) out[(size_t)row * CC + colg] = acc[rt][ct][r];
            }
        }
    }
}

extern "C" void kernel_launch(void* const* d_in, const int* in_sizes, int n_in,
                              void* d_out, int out_size, void* d_ws, size_t ws_size,
                              hipStream_t stream) {
    const float* x   = (const float*)d_in[0];
    const int*   ei  = (const int*)d_in[1];
    const float* Wl[3]  = {(const float*)d_in[2],  (const float*)d_in[7],  (const float*)d_in[12]};
    const float* bl[3]  = {(const float*)d_in[3],  (const float*)d_in[8],  (const float*)d_in[13]};
    const float* Wr[3]  = {(const float*)d_in[4],  (const float*)d_in[9],  (const float*)d_in[14]};
    const float* bng[3] = {(const float*)d_in[5],  (const float*)d_in[10], (const float*)d_in[15]};
    const float* bnb[3] = {(const float*)d_in[6],  (const float*)d_in[11], (const float*)d_in[16]};
    const float* linW = (const float*)d_in[17];
    const float* linb = (const float*)d_in[18];

    char* ws = (char*)d_ws;
    unsigned short* xb   = (unsigned short*)(ws + OFF_XB);
    unsigned short* mb   = (unsigned short*)(ws + OFF_MB);
    unsigned short* hb   = (unsigned short*)(ws + OFF_HB);
    unsigned char*  xq   = (unsigned char*)(ws + OFF_XQ);
    int*            bin  = (int*)(ws + OFF_BIN);
    int*            csr  = (int*)(ws + OFF_CSR);
    int*            rp   = (int*)(ws + OFF_RP);
    int*            cur  = (int*)(ws + OFF_CUR);
    unsigned short* wfr  = (unsigned short*)(ws + OFF_W);
    float*          st   = (float*)(ws + OFF_ST);

    k_prep<<<6658, 256, 0, stream>>>(Wl[0], Wr[0], Wl[1], Wr[1], Wl[2], Wr[2], linW, wfr,
                                     x, xb, xq, cur);
    k_bin<<<512, 256, 0, stream>>>(ei, cur, bin);
    k_build<<<NB, 256, 0, stream>>>(cur, rp, bin, csr);

    for (int l = 0; l < 3; ++l) {
        const unsigned short* wfp = wfr + (size_t)l * 32768;
        k_agg<<<25000, 256, 0, stream>>>(rp, csr, xq, mb, st);
        k_gemm<<<GB, 512, 0, stream>>>(xb, mb, wfp, bl[l], hb, st);
        if (l < 2)
            k_bn<<<6250, 256, 0, stream>>>(hb, st, bng[l], bnb[l], xb, xq);
    }
    k_bnfinal<<<GB, 256, 0, stream>>>(hb, xb, st, bng[2], bnb[2], wfr + 98304, linb,
                                      (float*)d_out);
}